// Round 12
// baseline (42.996 us; speedup 1.0000x reference)
//
#include <hip/hip_runtime.h>

#define NR    8192
#define ALPHA 0.2f
#define NCH   512          // chunks
#define CSZ   16           // elements per chunk

__device__ inline unsigned enc_f32(float f) {
    unsigned u = __float_as_uint(f);
    return (u & 0x80000000u) ? ~u : (u | 0x80000000u);
}
__device__ inline float dec_f32(unsigned u) {
    return __uint_as_float((u & 0x80000000u) ? (u ^ 0x80000000u) : ~u);
}

// kA: H = X@W, f1, f2->enc key. 512 blocks x 16 rows.
// 2-col-per-thread layout: thread (ks, rowq, cb) computes rows rowq*4..+3,
// cols {cb, cb+32}, k-slice ks*64..+63 -> each LDS read feeds 2 FMA chains
// (ratio 8:1 vs 4:1), halving the ds_read stream per row.
__global__ __launch_bounds__(256) void kA(
    const float* __restrict__ X, const float* __restrict__ W, const float* __restrict__ aa,
    float* __restrict__ H, float* __restrict__ F1, unsigned* __restrict__ ENC)
{
    __shared__ __align__(16) float xs[16 * 128];     // 8 KB
    __shared__ float part[16 * 2 * 64];              // 8 KB
    const int tid = threadIdx.x;
    const int ks   = tid >> 7;          // k-slice 0/1 (64 wide)
    const int rowq = (tid >> 5) & 3;    // row quartet 0..3
    const int cb   = tid & 31;          // columns cb, cb+32
    const int R0 = blockIdx.x * 16;

    float Wa[64], Wb[64];
#pragma unroll
    for (int e = 0; e < 64; ++e) {
        Wa[e] = W[(ks * 64 + e) * 64 + cb];
        Wb[e] = W[(ks * 64 + e) * 64 + cb + 32];
    }
    {
        const float4* X4 = (const float4*)(X + R0 * 128);
        float4* xs4 = (float4*)xs;
        xs4[tid] = X4[tid];
        xs4[256 + tid] = X4[256 + tid];
    }
    __syncthreads();

    float accA[4], accB[4];
#pragma unroll
    for (int rr = 0; rr < 4; ++rr) { accA[rr] = 0.f; accB[rr] = 0.f; }
    for (int rr = 0; rr < 4; ++rr) {
        const int r = rowq * 4 + rr;
        const float4* xr4 = (const float4*)&xs[r * 128 + ks * 64];
        float a0 = 0.f, b0 = 0.f;
#pragma unroll
        for (int e = 0; e < 16; ++e) {
            float4 xv = xr4[e];
            a0 = fmaf(xv.x, Wa[e * 4 + 0], a0);  b0 = fmaf(xv.x, Wb[e * 4 + 0], b0);
            a0 = fmaf(xv.y, Wa[e * 4 + 1], a0);  b0 = fmaf(xv.y, Wb[e * 4 + 1], b0);
            a0 = fmaf(xv.z, Wa[e * 4 + 2], a0);  b0 = fmaf(xv.z, Wb[e * 4 + 2], b0);
            a0 = fmaf(xv.w, Wa[e * 4 + 3], a0);  b0 = fmaf(xv.w, Wb[e * 4 + 3], b0);
        }
        accA[rr] = a0; accB[rr] = b0;
    }
#pragma unroll
    for (int rr = 0; rr < 4; ++rr) {
        const int r = rowq * 4 + rr;
        part[(r * 2 + ks) * 64 + cb]      = accA[rr];
        part[(r * 2 + ks) * 64 + cb + 32] = accB[rr];
    }
    __syncthreads();

    // epilogue: thread (w, c) handles rows w*4..w*4+3, column c
    const int w = tid >> 6, c = tid & 63;
    const float a1 = aa[c], a2 = aa[64 + c];
    for (int rr = 0; rr < 4; ++rr) {
        const int r = w * 4 + rr, i = R0 + r;
        float h = part[(r * 2 + 0) * 64 + c] + part[(r * 2 + 1) * 64 + c];
        H[i * 64 + c] = h;
        float v1 = h * a1, v2 = h * a2;
#pragma unroll
        for (int m = 32; m >= 1; m >>= 1) {
            v1 += __shfl_xor(v1, m, 64);
            v2 += __shfl_xor(v2, m, 64);
        }
        if (c == 0) { F1[i] = v1; ENC[i] = enc_f32(v2); }
    }
}

// kB: exact tie-broken ranks via 64-bit sortkeys (enc<<13|idx), registers only.
// 1024 blocks x 8 j's. Thresholds block-uniform (scalar path). 32 keys/thread.
__global__ __launch_bounds__(256) void kB(
    const unsigned* __restrict__ ENC, float* __restrict__ SF2, int* __restrict__ PERM)
{
    __shared__ unsigned cw[4 * 8];
    const int tid = threadIdx.x, bid = blockIdx.x;
    const uint4* E4 = (const uint4*)ENC;

    unsigned long long k64[32];
    {
        const unsigned base = tid * 4;
#pragma unroll
        for (int q = 0; q < 8; ++q) {
            uint4 v = E4[q * 256 + tid];
            const unsigned ib = q * 1024 + base;
            k64[q * 4 + 0] = ((unsigned long long)v.x << 13) | (ib + 0);
            k64[q * 4 + 1] = ((unsigned long long)v.y << 13) | (ib + 1);
            k64[q * 4 + 2] = ((unsigned long long)v.z << 13) | (ib + 2);
            k64[q * 4 + 3] = ((unsigned long long)v.w << 13) | (ib + 3);
        }
    }

    unsigned cnt[8];
#pragma unroll
    for (int jj = 0; jj < 8; ++jj) {
        const int j = bid * 8 + jj;                          // block-uniform
        const unsigned long long th = ((unsigned long long)ENC[j] << 13) | (unsigned)j;
        unsigned cjj = 0;
#pragma unroll
        for (int q = 0; q < 32; ++q) cjj += (unsigned)(k64[q] < th);
        cnt[jj] = cjj;
    }
#pragma unroll
    for (int jj = 0; jj < 8; ++jj) {
        unsigned v = cnt[jj];
#pragma unroll
        for (int m = 32; m >= 1; m >>= 1) v += (unsigned)__shfl_xor((int)v, m, 64);
        cnt[jj] = v;
    }
    const int w = tid >> 6;
    if ((tid & 63) == 0) {
#pragma unroll
        for (int jj = 0; jj < 8; ++jj) cw[w * 8 + jj] = cnt[jj];
    }
    __syncthreads();
    if (tid < 8) {
        const unsigned r = cw[tid] + cw[8 + tid] + cw[16 + tid] + cw[24 + tid];
        const int j = bid * 8 + tid;
        SF2[r] = dec_f32(ENC[j]);
        PERM[r] = j;
    }
}

// kC34: chunk sums (512 chunks x 16) + in-LDS scan. 65 blocks x 1024 threads.
// Block cb<64 owns output column cb; block 64 owns scalar sums AND packs
// SPQJ float4 (sf2,P,Q,perm) + cs table.
__global__ __launch_bounds__(1024) void kC34(
    const float* __restrict__ H, const float* __restrict__ SF2, const int* __restrict__ PERM,
    float4* __restrict__ SPQJ, float* __restrict__ CHPx, float* __restrict__ CHQx,
    float* __restrict__ cs)
{
    __shared__ float preP[1024], preQ[1024];
    __shared__ float scP[NCH], scQ[NCH];
    const int t = threadIdx.x, cb = blockIdx.x;
    const float fm = SF2[NR - 1];
    float accP = 0.f, accQ = 0.f;

    const float4* S4 = (const float4*)(SF2 + t * 8);
    const int4*   P4 = (const int4*)(PERM + t * 8);
    float4 f0 = S4[0], f1v = S4[1];
    int4   j0 = P4[0], j1 = P4[1];
    float sv[8] = { f0.x, f0.y, f0.z, f0.w, f1v.x, f1v.y, f1v.z, f1v.w };
    int   jx[8] = { j0.x, j0.y, j0.z, j0.w, j1.x, j1.y, j1.z, j1.w };

    if (cb < 64) {
#pragma unroll
        for (int e = 0; e < 8; ++e) {
            const float d = sv[e] - fm;
            const float P = __expf(d), Q = __expf(ALPHA * d);
            const float hv = H[jx[e] * 64 + cb];
            accP = fmaf(P, hv, accP);
            accQ = fmaf(Q, hv, accQ);
        }
    } else {
#pragma unroll
        for (int e = 0; e < 8; ++e) {
            const float d = sv[e] - fm;
            const float P = __expf(d), Q = __expf(ALPHA * d);
            SPQJ[t * 8 + e] = make_float4(sv[e], P, Q, __int_as_float(jx[e]));
            accP += P; accQ += Q;
        }
        if (t < NCH) cs[t] = SF2[t * CSZ];
    }

    preP[t] = accP; preQ[t] = accQ;
    __syncthreads();
    float vP = 0.f, vQ = 0.f;
    if (t < NCH) {                       // chunk t = threads 2t, 2t+1
        vP = preP[2 * t] + preP[2 * t + 1];
        vQ = preQ[2 * t] + preQ[2 * t + 1];
        scP[t] = vP; scQ[t] = vQ;
    }
    __syncthreads();
    for (int off = 1; off < NCH; off <<= 1) {
        float uP = 0.f, uQ = 0.f;
        if (t < NCH && t >= off) { uP = scP[t - off]; uQ = scQ[t - off]; }
        __syncthreads();
        if (t < NCH) { scP[t] += uP; scQ[t] += uQ; }
        __syncthreads();
    }
    if (t < NCH) {
        const float eP = (t > 0) ? scP[t - 1] : 0.f;     // exclusive
        const float eQ = (t > 0) ? scQ[t - 1] : 0.f;
        CHPx[t * 65 + cb] = eP;
        CHQx[t * 65 + cb] = eQ;
        if (t == NCH - 1) { CHPx[NCH * 65 + cb] = scP[t]; CHQx[NCH * 65 + cb] = scQ[t]; }
    }
}

// kD: per-row bsearch (cs in LDS, 9 steps) + 16-elem exact predicated correction
// (one SPQJ float4 per element) + elu. 2048 blocks x 4 rows (1 row/wave).
__global__ __launch_bounds__(256) void kD(
    const float* __restrict__ H, const float* __restrict__ F1, const float* __restrict__ SF2,
    const float4* __restrict__ SPQJ, const float* __restrict__ CHPx,
    const float* __restrict__ CHQx, const float* __restrict__ cs, float* __restrict__ OUT)
{
    __shared__ float sb[NCH];
    const int tid = threadIdx.x, w = tid >> 6, c = tid & 63, bid = blockIdx.x;
    sb[tid] = cs[tid];
    sb[256 + tid] = cs[256 + tid];
    __syncthreads();

    const float fm = SF2[NR - 1];
    const float Ptot = CHPx[NCH * 65 + c], ptot = CHPx[NCH * 65 + 64];
    const int i = bid * 4 + w;

    const float f1 = F1[i];
    const float s = f1 + fm;
    const float mrow = fmaxf(s, ALPHA * s);
    const float A = __expf(s - mrow);
    const float B = __expf(ALPHA * s - mrow);
    const float th = -f1;

    int lo = 0, hi = NCH;
    while (lo < hi) { int mid = (lo + hi) >> 1; if (sb[mid] < th) lo = mid + 1; else hi = mid; }
    const int b = lo > 0 ? lo - 1 : 0;
    const int t0 = b * CSZ;

    float qv = CHQx[b * 65 + c],  pp = CHPx[b * 65 + c];
    float qs = CHQx[b * 65 + 64], ps = CHPx[b * 65 + 64];
#pragma unroll
    for (int tt = 0; tt < CSZ; ++tt) {
        const float4 v = SPQJ[t0 + tt];         // wave-uniform 16B broadcast
        const int jv = __float_as_int(v.w);
        const float hv = H[jv * 64 + c];        // coalesced 256B row
        const bool cd = v.x < th;
        const float cP = cd ? v.y : 0.f, cQ = cd ? v.z : 0.f;
        qv = fmaf(cQ, hv, qv); qs += cQ;
        pp = fmaf(cP, hv, pp); ps += cP;
    }
    const float Pvec = Ptot - pp;
    const float pden = ptot - ps;
    const float num = A * Pvec + B * qv;
    const float den = A * pden + B * qs;
    const float feat = num / den;
    OUT[i * 64 + c] = feat > 0.f ? feat : expm1f(feat);
}

extern "C" void kernel_launch(void* const* d_in, const int* in_sizes, int n_in,
                              void* d_out, int out_size, void* d_ws, size_t ws_size,
                              hipStream_t stream) {
    const float* X = (const float*)d_in[0];   // 8192 x 128
    const float* W = (const float*)d_in[1];   // 128 x 64
    const float* a = (const float*)d_in[2];   // 128 x 1
    float* OUT = (float*)d_out;               // 8192 x 64

    float*    ws   = (float*)d_ws;
    float*    H    = ws;                         // 524288
    float*    F1   = H + 524288;                 // 8192
    unsigned* ENC  = (unsigned*)(F1 + 8192);     // 8192
    float*    SF2  = (float*)(ENC + 8192);       // 8192
    int*      PERM = (int*)(SF2 + 8192);         // 8192
    float4*   SPQJ = (float4*)(PERM + 8192);     // 8192 float4 (16B-aligned)
    float*    CHPx = (float*)(SPQJ + 8192);      // 513*65
    float*    CHQx = CHPx + 513 * 65;            // 513*65
    float*    cs   = CHQx + 513 * 65;            // 512

    kA  <<<512,  256,  0, stream>>>(X, W, a, H, F1, ENC);
    kB  <<<1024, 256,  0, stream>>>(ENC, SF2, PERM);
    kC34<<<65,   1024, 0, stream>>>(H, SF2, PERM, SPQJ, CHPx, CHQx, cs);
    kD  <<<2048, 256,  0, stream>>>(H, F1, SF2, SPQJ, CHPx, CHQx, cs, OUT);
}